// Round 1
// baseline (234.592 us; speedup 1.0000x reference)
//
#include <hip/hip_runtime.h>
#include <cstdint>

// BinConv2dEval: y = conv3x3(x,W) + bias; out = (sign*y >= 0) ? 1 : 0
// x: [32][128][64][64] fp32 in {0,1};  W: [256][128][3][3] fp32 in {-1,0,1}
// bias: [256] integer-valued fp32; sign: [256] in {-1,+1}; out fp32 NCHW.
//
// Strategy: all-integer implicit GEMM with i8 MFMA (16x16x64).
//  ws layout: xt = i8 NHWC zero-padded [32][66][66][128]  (17,842,176 B)
//             wp = i8 [tap(9)][co(256)][ci(128)]          (  294,912 B)

#define NIMG 32
#define CIN  128
#define HH   64
#define WW   64
#define COUT 256
#define PH   66                       // padded spatial
#define XT_ROWSTRIDE (PH * CIN)       // 8448 bytes per padded row
#define XT_NSTRIDE   (PH * PH * CIN)  // 557568 bytes per image
#define XT_BYTES     ((size_t)NIMG * XT_NSTRIDE)
#define WP_TAPSTRIDE (COUT * CIN)     // 32768
#define WP_BYTES     ((size_t)9 * WP_TAPSTRIDE)

typedef int v4i __attribute__((ext_vector_type(4)));

// -------------------------------------------------------------------------
// Prepass: x fp32 NCHW -> i8 NHWC, zero-padded borders. One block per
// (padded row py, image n). LDS transpose tile [64 x][144-padded ci].
__global__ __launch_bounds__(256) void xt_prepass(const float* __restrict__ x,
                                                  int8_t* __restrict__ xt) {
    const int py = blockIdx.x;   // 0..65
    const int n  = blockIdx.y;   // 0..31
    const int t  = threadIdx.x;
    int8_t* rowbase = xt + (size_t)(n * PH + py) * XT_ROWSTRIDE;

    if (py == 0 || py == PH - 1) {          // pure pad row: zeros
        int4 z = {0, 0, 0, 0};
        for (int j = t; j < XT_ROWSTRIDE / 16; j += 256)
            ((int4*)rowbase)[j] = z;
        return;
    }

    __shared__ __align__(16) int8_t Ls[64 * 144];  // [x][ci], +16B row pad
    const int y  = py - 1;
    const int xq = t & 15;                  // float4 index along x
    const float4* xf = (const float4*)x;
#pragma unroll
    for (int j = 0; j < 8; ++j) {
        const int ci = (t >> 4) + j * 16;   // 0..127
        float4 v = xf[((size_t)(n * CIN + ci) * HH + y) * 16 + xq];
        const int xv = xq * 4;
        Ls[(xv + 0) * 144 + ci] = (int8_t)v.x;
        Ls[(xv + 1) * 144 + ci] = (int8_t)v.y;
        Ls[(xv + 2) * 144 + ci] = (int8_t)v.z;
        Ls[(xv + 3) * 144 + ci] = (int8_t)v.w;
    }
    __syncthreads();
    const int4 z = {0, 0, 0, 0};
    for (int j = t; j < XT_ROWSTRIDE / 16; j += 256) {   // 528 int4 chunks
        const int px  = j >> 3;             // 0..65
        const int col = (j & 7) * 16;
        int4 val;
        if (px == 0 || px == PH - 1) val = z;
        else                         val = *(const int4*)&Ls[(px - 1) * 144 + col];
        *(int4*)(rowbase + (size_t)j * 16) = val;
    }
}

// -------------------------------------------------------------------------
// Weight prepack: OIHW fp32 -> i8 [tap][co][ci]
__global__ __launch_bounds__(256) void w_prepack(const float* __restrict__ w,
                                                 int8_t* __restrict__ wp) {
    const int idx = blockIdx.x * 256 + threadIdx.x;   // 0..294911
    if (idx >= (int)WP_BYTES) return;
    const int tap = idx >> 15;          // /32768
    const int rem = idx & 32767;
    const int co  = rem >> 7;
    const int ci  = rem & 127;
    wp[idx] = (int8_t)w[(size_t)(co * CIN + ci) * 9 + tap];
}

// -------------------------------------------------------------------------
// async global->LDS, 16B/lane. LDS dest = m0 (wave-uniform) + lane*16.
// m0 is free for this on gfx9+ (DS ops no longer use m0).
__device__ __forceinline__ void glds16(const void* g, uint32_t lds_off) {
    asm volatile("s_mov_b32 m0, %0\n"
                 "global_load_lds_dwordx4 %1, off"
                 :: "s"(lds_off), "v"(g) : "memory");
}

// -------------------------------------------------------------------------
// Main GEMM: D[co][m] = sum_taps W_tap[co][ci] * X_tap[ci][m]
// block: 128co x 128m, 4 waves (each 64co x 64m as 4x4 of 16x16 tiles)
// K-iter: BK=64 (one mfma_i32_16x16x64_i8 k-step), 18 iters = 9 taps x 2.
__global__ __launch_bounds__(256) void binconv_gemm(
    const int8_t* __restrict__ xt, const int8_t* __restrict__ wp,
    const float* __restrict__ bias, const float* __restrict__ sign,
    float* __restrict__ out) {

    __shared__ __align__(16) int8_t smem[2 * 128 * 64];  // Ws | Xs, 8KiB each
    int8_t* Ws = smem;          // [co 128][k 64]
    int8_t* Xs = smem + 8192;   // [m 128][k 64]

    const int t    = threadIdx.x;
    const int wid  = t >> 6;
    const int lane = t & 63;
    const int bx   = blockIdx.x;            // 1024 m-blocks
    const int co0  = blockIdx.y * 128;      // 0 / 128
    const int n    = bx >> 5;
    const int y0   = (bx & 31) << 1;        // 2 image rows per block

    // staging source bases (tap 0, half 0, round 0); 16B per thread
    const int8_t* xg = xt + (size_t)n * XT_NSTRIDE + (size_t)y0 * XT_ROWSTRIDE
                     + (size_t)(t >> 2) * CIN + (t & 3) * 16;
    const int8_t* wg = wp + (size_t)(co0 + (t >> 2)) * CIN + (t & 3) * 16;

    const uint32_t ldsW0 = __builtin_amdgcn_readfirstlane(
        (uint32_t)(uintptr_t)Ws + (uint32_t)(wid * 1024));
    const uint32_t ldsX0 = __builtin_amdgcn_readfirstlane(
        (uint32_t)(uintptr_t)Xs + (uint32_t)(wid * 1024));

    v4i acc[4][4] = {};                     // [co-subtile][m-subtile]

    const int row    = lane & 15;
    const int quad   = lane >> 4;
    const int co_off = (wid >> 1) * 64;     // wave tile origin
    const int m_off  = (wid & 1) * 64;

#pragma unroll
    for (int tap = 0; tap < 9; ++tap) {
        const int ky = tap / 3, kx = tap % 3;
        const int8_t* xgt = xg + (ky * PH + kx) * CIN;
        const int8_t* wgt = wg + tap * WP_TAPSTRIDE;
#pragma unroll
        for (int half = 0; half < 2; ++half) {
            __syncthreads();  // previous iter's ds_reads done before restage
            glds16(xgt + half * 64,                ldsX0);
            glds16(xgt + half * 64 + XT_ROWSTRIDE, ldsX0 + 4096);
            glds16(wgt + half * 64,                ldsW0);
            glds16(wgt + half * 64 + 64 * CIN,     ldsW0 + 4096);
            asm volatile("s_waitcnt vmcnt(0)" ::: "memory");
            __syncthreads();

            v4i af[4], bf[4];
#pragma unroll
            for (int c = 0; c < 4; ++c)
                af[c] = *(const v4i*)&Ws[(co_off + c * 16 + row) * 64 + quad * 16];
#pragma unroll
            for (int m = 0; m < 4; ++m)
                bf[m] = *(const v4i*)&Xs[(m_off + m * 16 + row) * 64 + quad * 16];
#pragma unroll
            for (int c = 0; c < 4; ++c)
#pragma unroll
                for (int m = 0; m < 4; ++m)
                    acc[c][m] = __builtin_amdgcn_mfma_i32_16x16x64_i8(
                        af[c], bf[m], acc[c][m], 0, 0, 0);
        }
    }

    // Epilogue. D 16x16 layout: col = lane&15 (m), row = quad*4 + reg (co).
    const float* bco = bias + co0 + co_off;
    const float* sco = sign + co0 + co_off;
    float* outb = out + ((size_t)n * COUT + co0 + co_off) * (HH * WW)
                + y0 * WW + m_off;
#pragma unroll
    for (int c = 0; c < 4; ++c) {
#pragma unroll
        for (int r = 0; r < 4; ++r) {
            const int col_co = c * 16 + quad * 4 + r;
            const float bv = bco[col_co];
            const float sv = sco[col_co];
            float* orow = outb + (size_t)col_co * (HH * WW);
#pragma unroll
            for (int m = 0; m < 4; ++m) {
                const float yv = (float)acc[c][m][r] + bv;   // exact ints
                const bool on = (sv > 0.0f) ? (yv >= 0.0f) : (yv <= 0.0f);
                orow[m * 16 + row] = on ? 1.0f : 0.0f;
            }
        }
    }
}

// -------------------------------------------------------------------------
// Fallback (only if ws too small): naive direct conv, one thread per output.
__global__ __launch_bounds__(256) void naive_conv(
    const float* __restrict__ x, const float* __restrict__ w,
    const float* __restrict__ bias, const float* __restrict__ sign,
    float* __restrict__ out) {
    const int idx = blockIdx.x * 256 + threadIdx.x;
    const int xc = idx & 63, y = (idx >> 6) & 63, co = (idx >> 12) & 255,
              n = idx >> 20;
    float s = 0.f;
    for (int ci = 0; ci < CIN; ++ci)
        for (int ky = 0; ky < 3; ++ky) {
            const int iy = y + ky - 1;
            if (iy < 0 || iy >= HH) continue;
            for (int kx = 0; kx < 3; ++kx) {
                const int ix = xc + kx - 1;
                if (ix < 0 || ix >= WW) continue;
                s += x[((size_t)(n * CIN + ci) * HH + iy) * WW + ix] *
                     w[((size_t)(co * CIN + ci) * 3 + ky) * 3 + kx];
            }
        }
    const float yv = s + bias[co];
    out[idx] = ((sign[co] > 0.f) ? (yv >= 0.f) : (yv <= 0.f)) ? 1.0f : 0.0f;
}

// -------------------------------------------------------------------------
extern "C" void kernel_launch(void* const* d_in, const int* in_sizes, int n_in,
                              void* d_out, int out_size, void* d_ws, size_t ws_size,
                              hipStream_t stream) {
    const float* x    = (const float*)d_in[0];
    const float* w    = (const float*)d_in[1];
    const float* bias = (const float*)d_in[2];
    const float* sign = (const float*)d_in[3];
    float* out = (float*)d_out;

    const size_t need = XT_BYTES + WP_BYTES;   // ~18.1 MiB
    if (ws_size < need) {
        naive_conv<<<dim3((NIMG * COUT * HH * WW) / 256), 256, 0, stream>>>(
            x, w, bias, sign, out);
        return;
    }
    int8_t* xt = (int8_t*)d_ws;
    int8_t* wp = (int8_t*)d_ws + XT_BYTES;

    xt_prepass<<<dim3(PH, NIMG), 256, 0, stream>>>(x, xt);
    w_prepack<<<dim3((int)(WP_BYTES + 255) / 256), 256, 0, stream>>>(w, wp);
    binconv_gemm<<<dim3(NIMG * (HH / 2), COUT / 128), 256, 0, stream>>>(
        xt, wp, bias, sign, out);
}